// Round 5
// baseline (378.808 us; speedup 1.0000x reference)
//
#include <hip/hip_runtime.h>
#include <stdint.h>

// Per-row top-K magnitude masking, exact. x: (4096, 8192) fp32, K=819.
// ROUND 5: one row per WAVE, zero __syncthreads.
//   - 4 waves/block; wave w of block b owns row b*4+w, held in registers
//     (32 uint4 = 128 elems/lane).
//   - Wave-private 1024-bin LDS histogram (4 KB/wave). LDS ops from a single
//     wave execute in order -> no barriers needed at all.
//   - Exact radix select over the 31-bit abs pattern: 10+10+10 bit histogram
//     phases + final 1-bit ballot count. No candidate list, no caps, no
//     distribution assumptions.
//   - All cross-lane work via __shfl / __ballot (wave-local).
// Rationale: R2/R4 showed no pipe >27% busy; time went to the barrier-
// serialized phase chain. This removes every barrier.

constexpr int NCOLS = 8192;
constexpr int TPB   = 256;             // 4 waves
constexpr int WAVES = TPB / 64;
constexpr int V4R   = NCOLS / 4;       // 2048 uint4 per row
constexpr int V4L   = V4R / 64;        // 32 uint4 per lane
constexpr int BINS  = 1024;

__global__ __launch_bounds__(TPB, 3) void topk_row_kernel(const float* __restrict__ x,
                                                          float* __restrict__ out,
                                                          int K) {
  __shared__ uint32_t hist_all[WAVES * BINS];
  const int tid  = threadIdx.x;
  const int lane = tid & 63;
  const int wave = tid >> 6;
  const int row  = blockIdx.x * WAVES + wave;
  uint32_t* h = &hist_all[wave * BINS];

  // Load the wave's row: lane L takes uint4 c*64+L (1 KB contiguous per instr).
  const uint4* xr = (const uint4*)(x) + (size_t)row * V4R;
  uint4 v[V4L];
#pragma unroll
  for (int c = 0; c < V4L; ++c) v[c] = xr[c * 64 + lane];

  uint32_t rem = (uint32_t)K;
  uint32_t pfx = 0;   // selected high bits of the 31-bit key, accumulated

  // ---- 3 histogram phases: key bits [30..21], [20..11], [10..1] ----
#pragma unroll 1
  for (int phase = 0; phase < 3; ++phase) {
    const int dshift = 21 - 10 * phase;

    // Zero wave-private histogram (bank = lane%32 -> 2-way, free).
#pragma unroll
    for (int t = 0; t < BINS / 64; ++t) h[t * 64 + lane] = 0u;

    // Histogram candidates (phase 0: everything; else: prefix-matching only).
    if (phase == 0) {
#pragma unroll
      for (int c = 0; c < V4L; ++c) {
        atomicAdd(&h[(v[c].x & 0x7fffffffu) >> 21], 1u);
        atomicAdd(&h[(v[c].y & 0x7fffffffu) >> 21], 1u);
        atomicAdd(&h[(v[c].z & 0x7fffffffu) >> 21], 1u);
        atomicAdd(&h[(v[c].w & 0x7fffffffu) >> 21], 1u);
      }
    } else {
      const int cshift = dshift + 10;
#pragma unroll
      for (int c = 0; c < V4L; ++c) {
        uint32_t k;
        k = v[c].x & 0x7fffffffu; if ((k >> cshift) == pfx) atomicAdd(&h[(k >> dshift) & (BINS - 1)], 1u);
        k = v[c].y & 0x7fffffffu; if ((k >> cshift) == pfx) atomicAdd(&h[(k >> dshift) & (BINS - 1)], 1u);
        k = v[c].z & 0x7fffffffu; if ((k >> cshift) == pfx) atomicAdd(&h[(k >> dshift) & (BINS - 1)], 1u);
        k = v[c].w & 0x7fffffffu; if ((k >> cshift) == pfx) atomicAdd(&h[(k >> dshift) & (BINS - 1)], 1u);
      }
    }

    // Coarse: lane L owns bins [16L,16L+16). Rotated reads (4-way conflict).
    uint32_t Tl = 0;
#pragma unroll
    for (int t = 0; t < 16; ++t) Tl += h[lane * 16 + ((t + lane) & 15)];

    // Inclusive suffix scan across lanes (high lanes = high bins).
    uint32_t S = Tl;
#pragma unroll
    for (int off = 1; off < 64; off <<= 1) {
      uint32_t u = __shfl_down(S, off, 64);
      S += (lane + off < 64) ? u : 0u;
    }
    uint32_t Sx = S - Tl;                       // suffix excluding own chunk
    uint64_t bal = __ballot(S >= rem && Sx < rem);
    int W = __ffsll((unsigned long long)bal) - 1;      // winning 16-bin chunk
    uint32_t SxW = __shfl(Sx, W, 64);

    // Fine: all lanes read chunk W's bins (4-lane broadcast groups, free).
    uint32_t cv = h[W * 16 + (lane & 15)];
    uint32_t s2 = cv;
#pragma unroll
    for (int off = 1; off < 16; off <<= 1) {
      uint32_t u = __shfl_down(s2, off, 64);
      s2 += (((lane & 15) + off) < 16) ? u : 0u;
    }
    uint32_t s2x = s2 - cv;
    uint64_t bal2 = __ballot((SxW + s2) >= rem && (SxW + s2x) < rem);
    int LF = __ffsll((unsigned long long)bal2) - 1;
    uint32_t digit = (uint32_t)(W * 16 + (LF & 15));
    uint32_t SbinP1 = __shfl(SxW + s2x, LF, 64);
    rem -= SbinP1;
    pfx = (pfx << 10) | digit;
  }

  // ---- Final bit (key bit 0): count candidates with bit0 = 1 ----
  uint32_t c1 = 0;
#pragma unroll
  for (int c = 0; c < V4L; ++c) {
    uint32_t k;
    k = v[c].x & 0x7fffffffu; c1 += (uint32_t)((k >> 1) == pfx) & (k & 1u);
    k = v[c].y & 0x7fffffffu; c1 += (uint32_t)((k >> 1) == pfx) & (k & 1u);
    k = v[c].z & 0x7fffffffu; c1 += (uint32_t)((k >> 1) == pfx) & (k & 1u);
    k = v[c].w & 0x7fffffffu; c1 += (uint32_t)((k >> 1) == pfx) & (k & 1u);
  }
#pragma unroll
  for (int off = 1; off < 64; off <<= 1) {
    uint32_t u = __shfl_down(c1, off, 64);
    c1 += (lane + off < 64) ? u : 0u;
  }
  uint32_t c1tot = __shfl(c1, 0, 64);
  const uint32_t thr = (pfx << 1) | ((c1tot >= rem) ? 1u : 0u);  // exact K-th |x| bits

  // ---- Masked writeback ----
  uint4* outr = (uint4*)(out) + (size_t)row * V4R;
#pragma unroll
  for (int c = 0; c < V4L; ++c) {
    uint4 o = v[c];
    o.x = ((o.x & 0x7fffffffu) >= thr) ? o.x : 0u;
    o.y = ((o.y & 0x7fffffffu) >= thr) ? o.y : 0u;
    o.z = ((o.z & 0x7fffffffu) >= thr) ? o.z : 0u;
    o.w = ((o.w & 0x7fffffffu) >= thr) ? o.w : 0u;
    outr[c * 64 + lane] = o;
  }
}

extern "C" void kernel_launch(void* const* d_in, const int* in_sizes, int n_in,
                              void* d_out, int out_size, void* d_ws, size_t ws_size,
                              hipStream_t stream) {
  (void)n_in; (void)out_size; (void)d_ws; (void)ws_size;
  const float* x = (const float*)d_in[0];
  float* out = (float*)d_out;
  const int rows = in_sizes[0] / NCOLS;       // 4096
  const int K = (int)(0.1 * NCOLS + 0.5);     // round(819.2) = 819
  topk_row_kernel<<<rows / WAVES, TPB, 0, stream>>>(x, out, K);
}

// Round 6
// 275.778 us; speedup vs baseline: 1.3736x; 1.3736x over previous
//
#include <hip/hip_runtime.h>
#include <stdint.h>

// Per-row top-K magnitude masking, exact. x: (4096, 8192) fp32, K=819.
// ROUND 6: one row per WAVE, zero barriers, NO register-held row (R5's spill
// killed that). The wave streams its row from global three times:
//   S1: 1024-bin LDS histogram of abs-key bits 30..21 (wave-private, 4 KB)
//   -> wave shuffle/ballot suffix-scan: winning 10-bit digit d1 + rank rem
//   S2: compact the ~410 candidates (key>>21 == d1) into an LDS list
//       aliased on the dead histogram (ballot prefix slots, no atomics)
//   refine low 21 bits exactly from the LDS list (ballot/shuffle, n<=1024;
//   distribution-free fallback: per-bit global re-streams)
//   S3: re-stream row, mask against exact threshold, store.
// Re-streams are L3-hits (x = 128 MB < 256 MB Infinity Cache); FETCH counts
// HBM only. 16 independent wave-chains per CU, no convoy, no spill.

constexpr int NCOLS = 8192;
constexpr int TPB   = 256;            // 4 waves = 4 rows per block
constexpr int WAVES = TPB / 64;
constexpr int V4R   = NCOLS / 4;      // 2048 uint4 per row
constexpr int V4L   = V4R / 64;       // 32 uint4 per lane per stream
constexpr int BINS  = 1024;           // hist bins (key bits 30..21)
constexpr int LCAP  = 1024;           // candidate list capacity (aliases hist)

__device__ __forceinline__ uint32_t wave_suffix_incl(uint32_t v, int lane) {
#pragma unroll
  for (int off = 1; off < 64; off <<= 1) {
    uint32_t u = __shfl_down(v, off, 64);
    v += (lane + off < 64) ? u : 0u;
  }
  return v;
}

__device__ __forceinline__ uint32_t wave_sum_bcast(uint32_t v, int lane) {
#pragma unroll
  for (int off = 1; off < 64; off <<= 1) {
    uint32_t u = __shfl_down(v, off, 64);
    v += (lane + off < 64) ? u : 0u;
  }
  return __shfl(v, 0, 64);
}

__global__ __launch_bounds__(TPB) void topk_row_kernel(const float* __restrict__ x,
                                                       float* __restrict__ out,
                                                       int K) {
  __shared__ uint32_t lds[WAVES * BINS];   // 16 KB: per-wave hist, then list
  const int tid  = threadIdx.x;
  const int lane = tid & 63;
  const int wave = tid >> 6;
  const int row  = blockIdx.x * WAVES + wave;

  uint32_t* h = &lds[wave * BINS];
  const uint4* xr = (const uint4*)(x) + (size_t)row * V4R;

  // ---- zero wave-private histogram (in-order within wave, no barrier) ----
#pragma unroll
  for (int t = 0; t < BINS / 64; ++t) h[t * 64 + lane] = 0u;

  // ---- S1: histogram key bits 30..21 ----
#pragma unroll 8
  for (int c = 0; c < V4L; ++c) {
    uint4 w = xr[c * 64 + lane];
    atomicAdd(&h[(w.x & 0x7fffffffu) >> 21], 1u);
    atomicAdd(&h[(w.y & 0x7fffffffu) >> 21], 1u);
    atomicAdd(&h[(w.z & 0x7fffffffu) >> 21], 1u);
    atomicAdd(&h[(w.w & 0x7fffffffu) >> 21], 1u);
  }

  // ---- scan: coarse (16 bins/lane) + fine (winning chunk) ----
  uint32_t rem = (uint32_t)K;
  uint32_t Tl = 0;
#pragma unroll
  for (int q = 0; q < 4; ++q) {
    uint4 t4 = *(const uint4*)&h[lane * 16 + q * 4];
    Tl += t4.x + t4.y + t4.z + t4.w;
  }
  uint32_t S = wave_suffix_incl(Tl, lane);
  uint32_t Sx = S - Tl;
  uint64_t bal = __ballot(S >= rem && Sx < rem);
  int W = __ffsll((unsigned long long)bal) - 1;   // winning 16-bin chunk
  uint32_t SxW = __shfl(Sx, W, 64);

  uint32_t cv = h[W * 16 + (lane & 15)];          // 4-group broadcast read
  uint32_t s2 = cv;
#pragma unroll
  for (int off = 1; off < 16; off <<= 1) {
    uint32_t u = __shfl_down(s2, off, 64);
    s2 += (((lane & 15) + off) < 16) ? u : 0u;
  }
  uint32_t s2x = s2 - cv;
  uint64_t bal2 = __ballot((SxW + s2) >= rem && (SxW + s2x) < rem);
  int LF = __ffsll((unsigned long long)bal2) - 1;
  const uint32_t d1 = (uint32_t)(W * 16 + (LF & 15));
  rem -= __shfl(SxW + s2x, LF, 64);               // rank within bin d1

  // ---- S2: compact candidates (key>>21 == d1) into list (aliases hist) ----
  uint32_t* list = h;                              // hist dead from here
  uint32_t base = 0;
#pragma unroll 8
  for (int c = 0; c < V4L; ++c) {
    uint4 w = xr[c * 64 + lane];
    uint32_t kk[4] = {w.x & 0x7fffffffu, w.y & 0x7fffffffu,
                      w.z & 0x7fffffffu, w.w & 0x7fffffffu};
#pragma unroll
    for (int j = 0; j < 4; ++j) {
      bool m = (kk[j] >> 21) == d1;
      uint64_t b = __ballot(m);
      if (m) {
        uint32_t off = (uint32_t)__popcll(b & ((1ull << lane) - 1ull));
        uint32_t idx = base + off;
        if (idx < LCAP) list[idx] = kk[j];
      }
      base += (uint32_t)__popcll(b);
    }
  }
  const uint32_t n = base;                         // uniform across lanes

  // ---- exact refinement of key bits 20..0 ----
  uint32_t pfx = d1;                               // grows to full 31-bit key
  if (n <= LCAP) {
    const uint32_t jmax = (n + 63) >> 6;
#pragma unroll 1
    for (int b = 20; b >= 0; --b) {
      uint32_t cl = 0;
      for (uint32_t j = 0; j < jmax; ++j) {
        uint32_t idx = j * 64 + lane;
        if (idx < n) {
          uint32_t key = list[idx];                // [j*64+lane]: conflict-free
          cl += ((key >> (b + 1)) == pfx) & ((key >> b) & 1u);
        }
      }
      uint32_t c1 = wave_sum_bcast(cl, lane);
      if (c1 >= rem) pfx = (pfx << 1) | 1u;
      else           { rem -= c1; pfx <<= 1; }
    }
  } else {
    // Fallback (n > LCAP; impossible for Gaussian rows, kept for generality):
    // per-bit counting via global re-streams. Slow but exact.
#pragma unroll 1
    for (int b = 20; b >= 0; --b) {
      uint32_t cl = 0;
      for (int c = 0; c < V4L; ++c) {
        uint4 w = xr[c * 64 + lane];
        uint32_t kk[4] = {w.x & 0x7fffffffu, w.y & 0x7fffffffu,
                          w.z & 0x7fffffffu, w.w & 0x7fffffffu};
#pragma unroll
        for (int j = 0; j < 4; ++j)
          cl += ((kk[j] >> (b + 1)) == pfx) & ((kk[j] >> b) & 1u);
      }
      uint32_t c1 = wave_sum_bcast(cl, lane);
      if (c1 >= rem) pfx = (pfx << 1) | 1u;
      else           { rem -= c1; pfx <<= 1; }
    }
  }
  const uint32_t thr = pfx;                        // exact K-th largest |x| bits

  // ---- S3: re-stream, mask, store ----
  uint4* outr = (uint4*)(out) + (size_t)row * V4R;
#pragma unroll 8
  for (int c = 0; c < V4L; ++c) {
    uint4 o = xr[c * 64 + lane];
    o.x = ((o.x & 0x7fffffffu) >= thr) ? o.x : 0u;
    o.y = ((o.y & 0x7fffffffu) >= thr) ? o.y : 0u;
    o.z = ((o.z & 0x7fffffffu) >= thr) ? o.z : 0u;
    o.w = ((o.w & 0x7fffffffu) >= thr) ? o.w : 0u;
    outr[c * 64 + lane] = o;
  }
}

extern "C" void kernel_launch(void* const* d_in, const int* in_sizes, int n_in,
                              void* d_out, int out_size, void* d_ws, size_t ws_size,
                              hipStream_t stream) {
  (void)n_in; (void)out_size; (void)d_ws; (void)ws_size;
  const float* x = (const float*)d_in[0];
  float* out = (float*)d_out;
  const int rows = in_sizes[0] / NCOLS;            // 4096
  const int K = (int)(0.1 * NCOLS + 0.5);          // round(819.2) = 819
  topk_row_kernel<<<rows / WAVES, TPB, 0, stream>>>(x, out, K);
}

// Round 7
// 241.771 us; speedup vs baseline: 1.5668x; 1.1407x over previous
//
#include <hip/hip_runtime.h>
#include <stdint.h>

// Per-row top-K magnitude masking, exact. x: (4096, 8192) fp32, K=819.
// ROUND 7: prune-then-select.
//   - Block-per-row, row in registers (8 x uint4/thread -- R4's proven 48-VGPR
//     pattern). ONE global read, ONE global write (minimal traffic).
//   - Prune: compact |x| >= 1.25 (bit cmp) into per-wave LDS segments via
//     ballot prefix (no atomics). n ~ 1730 of 8192. Validity: K-th largest
//     >= 1.25  <=>  n >= K (checked; exact fallback otherwise).
//   - Select: wave 0 alone radix-selects the exact K-th among the n LDS keys:
//     3 x 1024-bin histogram passes (bits 30..21, 20..11, 10..1) + final bit,
//     all single-wave (in-order LDS, no barriers inside).
//   - 2 block barriers total. Select phase ~8x shorter than R4's full-row
//     histogram -> memory phases dominate the chain -> higher HBM duty.
//   - Fallback (n < K or segment overflow; never for Gaussian rows): exact
//     distributed 31-round bitwise select over the register-held row.

constexpr int NCOLS = 8192;
constexpr int TPB   = 256;
constexpr int V4    = NCOLS / 4;     // 2048 uint4 per row
constexpr int VPT   = V4 / TPB;      // 8 uint4 per thread
constexpr int SEGCAP = 1024;         // per-wave candidate segment capacity
constexpr int BINS  = 1024;
constexpr uint32_t PRUNE = 0x3FA00000u;  // bit pattern of 1.25f

struct alignas(16) Shared {
  uint32_t seg[4][SEGCAP];   // 16 KB candidate segments (per wave)
  uint32_t hist[BINS];       // 4 KB select histogram (wave-0 private use)
  uint32_t segcnt[4];        // true per-wave candidate counts
  uint32_t wavered[4];       // fallback block-reduce scratch
  uint32_t thr_s;            // final threshold bit pattern
};

__global__ __launch_bounds__(TPB) void topk_row_kernel(const float* __restrict__ x,
                                                       float* __restrict__ out,
                                                       int K) {
  __shared__ Shared sh;
  const int tid  = threadIdx.x;
  const int lane = tid & 63;
  const int wave = tid >> 6;
  const int row  = blockIdx.x;

  // ---- single global read: row -> registers ----
  const uint4* xr = (const uint4*)(x) + (size_t)row * V4;
  uint4 v[VPT];
#pragma unroll
  for (int i = 0; i < VPT; ++i) v[i] = xr[tid + i * TPB];

  // ---- prune-compact into this wave's LDS segment (ballot prefix) ----
  uint32_t base = 0;
#pragma unroll
  for (int i = 0; i < VPT; ++i) {
    uint32_t kk[4] = {v[i].x & 0x7fffffffu, v[i].y & 0x7fffffffu,
                      v[i].z & 0x7fffffffu, v[i].w & 0x7fffffffu};
#pragma unroll
    for (int j = 0; j < 4; ++j) {
      bool m = kk[j] >= PRUNE;
      uint64_t b = __ballot(m);
      if (m) {
        uint32_t off = (uint32_t)__popcll(b & ((1ull << lane) - 1ull));
        uint32_t idx = base + off;
        if (idx < SEGCAP) sh.seg[wave][idx] = kk[j];
      }
      base += (uint32_t)__popcll(b);
    }
  }
  if (lane == 0) sh.segcnt[wave] = base;   // true count (may exceed SEGCAP)
  __syncthreads();                          // (1)

  const uint32_t n0 = sh.segcnt[0], n1 = sh.segcnt[1],
                 n2 = sh.segcnt[2], n3 = sh.segcnt[3];
  const uint32_t ntot = n0 + n1 + n2 + n3;
  const bool ok = (ntot >= (uint32_t)K) &&
                  n0 <= SEGCAP && n1 <= SEGCAP && n2 <= SEGCAP && n3 <= SEGCAP;

  if (ok) {
    // ---- wave 0: exact K-th largest among the ntot candidates ----
    if (wave == 0) {
      uint32_t rem = (uint32_t)K;
      uint32_t pfx = 0;                    // selected high bits of the 31-bit key
#pragma unroll 1
      for (int pass = 0; pass < 3; ++pass) {
        const int dsh = 21 - 10 * pass;    // digit shift; condition shift = dsh+10
        // zero hist (single wave: LDS in-order, no barrier)
        for (int t = lane; t < BINS; t += 64) sh.hist[t] = 0u;
        // accumulate candidates matching prefix
        for (int w = 0; w < 4; ++w) {
          const uint32_t nw = sh.segcnt[w];
          for (uint32_t j = lane; j < nw; j += 64) {
            uint32_t key = sh.seg[w][j];
            if ((key >> (dsh + 10)) == pfx)   // pass 0: key>>31==0 always
              atomicAdd(&sh.hist[(key >> dsh) & (BINS - 1)], 1u);
          }
        }
        // coarse scan: lane owns 16 bins (rotated reads)
        uint32_t Tl = 0;
#pragma unroll
        for (int t = 0; t < 16; ++t) Tl += sh.hist[lane * 16 + ((t + lane) & 15)];
        uint32_t S = Tl;
#pragma unroll
        for (int off = 1; off < 64; off <<= 1) {
          uint32_t u = __shfl_down(S, off, 64);
          S += (lane + off < 64) ? u : 0u;
        }
        uint32_t Sx = S - Tl;
        uint64_t bal = __ballot(S >= rem && Sx < rem);
        int W = __ffsll((unsigned long long)bal) - 1;
        uint32_t SxW = __shfl(Sx, W, 64);
        // fine scan within winning 16-bin chunk
        uint32_t cv = sh.hist[W * 16 + (lane & 15)];
        uint32_t s2 = cv;
#pragma unroll
        for (int off = 1; off < 16; off <<= 1) {
          uint32_t u = __shfl_down(s2, off, 64);
          s2 += (((lane & 15) + off) < 16) ? u : 0u;
        }
        uint32_t s2x = s2 - cv;
        uint64_t bal2 = __ballot((SxW + s2) >= rem && (SxW + s2x) < rem);
        int LF = __ffsll((unsigned long long)bal2) - 1;
        uint32_t digit = (uint32_t)(W * 16 + (LF & 15));
        rem -= __shfl(SxW + s2x, LF, 64);
        pfx = (pfx << 10) | digit;
      }
      // final bit (key bit 0)
      uint32_t cl = 0;
      for (int w = 0; w < 4; ++w) {
        const uint32_t nw = sh.segcnt[w];
        for (uint32_t j = lane; j < nw; j += 64) {
          uint32_t key = sh.seg[w][j];
          cl += (uint32_t)((key >> 1) == pfx) & (key & 1u);
        }
      }
#pragma unroll
      for (int off = 1; off < 64; off <<= 1) {
        uint32_t u = __shfl_down(cl, off, 64);
        cl += (lane + off < 64) ? u : 0u;
      }
      uint32_t c1 = __shfl(cl, 0, 64);
      if (lane == 0) sh.thr_s = (pfx << 1) | ((c1 >= rem) ? 1u : 0u);
    }
  } else {
    // ---- exact fallback: distributed bitwise select over register row ----
    uint32_t rem = (uint32_t)K;
    uint32_t pfx = 0;
#pragma unroll 1
    for (int b = 30; b >= 0; --b) {
      uint32_t cl = 0;
#pragma unroll
      for (int i = 0; i < VPT; ++i) {
        uint32_t kk[4] = {v[i].x & 0x7fffffffu, v[i].y & 0x7fffffffu,
                          v[i].z & 0x7fffffffu, v[i].w & 0x7fffffffu};
#pragma unroll
        for (int j = 0; j < 4; ++j)
          cl += (uint32_t)((kk[j] >> (b + 1)) == pfx) & ((kk[j] >> b) & 1u);
      }
#pragma unroll
      for (int off = 1; off < 64; off <<= 1) {
        uint32_t u = __shfl_down(cl, off, 64);
        cl += (lane + off < 64) ? u : 0u;
      }
      if (lane == 0) sh.wavered[wave] = cl;
      __syncthreads();
      uint32_t c1 = sh.wavered[0] + sh.wavered[1] + sh.wavered[2] + sh.wavered[3];
      if (c1 >= rem) pfx = (pfx << 1) | 1u;
      else           { rem -= c1; pfx <<= 1; }
      __syncthreads();
    }
    if (tid == 0) sh.thr_s = pfx;
  }
  __syncthreads();                          // (2)
  const uint32_t thr = sh.thr_s;            // exact K-th largest |x| bits

  // ---- masked writeback from registers ----
  uint4* outr = (uint4*)(out) + (size_t)row * V4;
#pragma unroll
  for (int i = 0; i < VPT; ++i) {
    uint4 o = v[i];
    o.x = ((o.x & 0x7fffffffu) >= thr) ? o.x : 0u;
    o.y = ((o.y & 0x7fffffffu) >= thr) ? o.y : 0u;
    o.z = ((o.z & 0x7fffffffu) >= thr) ? o.z : 0u;
    o.w = ((o.w & 0x7fffffffu) >= thr) ? o.w : 0u;
    outr[tid + i * TPB] = o;
  }
}

extern "C" void kernel_launch(void* const* d_in, const int* in_sizes, int n_in,
                              void* d_out, int out_size, void* d_ws, size_t ws_size,
                              hipStream_t stream) {
  (void)n_in; (void)out_size; (void)d_ws; (void)ws_size;
  const float* x = (const float*)d_in[0];
  float* out = (float*)d_out;
  const int rows = in_sizes[0] / NCOLS;     // 4096
  const int K = (int)(0.1 * NCOLS + 0.5);   // round(819.2) = 819
  topk_row_kernel<<<rows, TPB, 0, stream>>>(x, out, K);
}